// Round 7
// baseline (27.693 us; speedup 1.0000x reference)
//
#include <hip/hip_runtime.h>

#define MARGIN 0.3f
#define ANCHOR 0.5f
#define EPS    1e-8f
#define NSLOT  32        // accumulator slots, each on its own 64B line

typedef unsigned long long ull;

// ws accumulator layout (all 64B-padded):
//   gsum[k] : ws + k*64            (double)
//   gcnt[k] : ws + 2048 + k*64     (unsigned)
//   arr[k]  : ws + 4096 + k*64     (unsigned)
//   master  : ws + 6144            (unsigned)
//   sq[N]   : ws + 8192            (float)
//   qual[N] : sq + N               (float)

// ---------------- kernel 1: s_q, quality, accumulator zero-init ----------------
// 4 rows per wave, q held in registers; 512 blocks.
__global__ __launch_bounds__(256) void sq_kernel(
        const float* __restrict__ q, const float* __restrict__ d,
        const float* __restrict__ rates,
        float* __restrict__ sq, float* __restrict__ qual,
        char* __restrict__ acc, int N, int D) {
    int tid = threadIdx.x;
    if (blockIdx.x == 0) {
        if (tid < NSLOT)              *(double*)  (acc + (size_t)tid * 64)               = 0.0;
        else if (tid < 2 * NSLOT)     *(unsigned*)(acc + 2048 + (size_t)(tid - 32) * 64) = 0u;
        else if (tid < 3 * NSLOT)     *(unsigned*)(acc + 4096 + (size_t)(tid - 64) * 64) = 0u;
        else if (tid == 3 * NSLOT)    *(unsigned*)(acc + 6144)                           = 0u;
    }
    const int lane  = tid & 63;
    const int wid   = (blockIdx.x * blockDim.x + tid) >> 6;   // global wave id
    const int nwav  = (gridDim.x * blockDim.x) >> 6;
    const int it0   = lane * 4;                               // lane's column offset

    // q in registers (D = 1024 -> 4 float4 per lane at stride 256 floats)
    float4 q0 = *(const float4*)(q + it0);
    float4 q1 = *(const float4*)(q + it0 + 256);
    float4 q2 = *(const float4*)(q + it0 + 512);
    float4 q3 = *(const float4*)(q + it0 + 768);
    float qn  = q0.x*q0.x + q0.y*q0.y + q0.z*q0.z + q0.w*q0.w
              + q1.x*q1.x + q1.y*q1.y + q1.z*q1.z + q1.w*q1.w
              + q2.x*q2.x + q2.y*q2.y + q2.z*q2.z + q2.w*q2.w
              + q3.x*q3.x + q3.y*q3.y + q3.z*q3.z + q3.w*q3.w;

    for (int row = wid; row < N; row += nwav) {
        const float* r = d + (size_t)row * (size_t)D;
        float4 d0 = *(const float4*)(r + it0);
        float4 d1 = *(const float4*)(r + it0 + 256);
        float4 d2 = *(const float4*)(r + it0 + 512);
        float4 d3 = *(const float4*)(r + it0 + 768);

        float dot = d0.x*q0.x + d0.y*q0.y + d0.z*q0.z + d0.w*q0.w
                  + d1.x*q1.x + d1.y*q1.y + d1.z*q1.z + d1.w*q1.w
                  + d2.x*q2.x + d2.y*q2.y + d2.z*q2.z + d2.w*q2.w
                  + d3.x*q3.x + d3.y*q3.y + d3.z*q3.z + d3.w*q3.w;
        float dn  = d0.x*d0.x + d0.y*d0.y + d0.z*d0.z + d0.w*d0.w
                  + d1.x*d1.x + d1.y*d1.y + d1.z*d1.z + d1.w*d1.w
                  + d2.x*d2.x + d2.y*d2.y + d2.z*d2.z + d2.w*d2.w
                  + d3.x*d3.x + d3.y*d3.y + d3.z*d3.z + d3.w*d3.w;

        float dq = dot, dd = dn, qq = qn;
        #pragma unroll
        for (int off = 32; off >= 1; off >>= 1) {
            dq += __shfl_xor(dq, off);
            dd += __shfl_xor(dd, off);
            qq += __shfl_xor(qq, off);
        }
        if (lane == 0) {
            float den = fmaxf(sqrtf(dd) * sqrtf(qq), EPS);
            sq[row]   = dq / den;
            qual[row] = fabsf(rates[row] - ANCHOR);
        }
    }
}

// ------- kernel 2: N^2 pair partials; 512 blocks; i-state in regs across j ------
// grid = (N/256, N/512). Thread owns i for the whole block; j loops 512 with
// wave-uniform float4 reads. Fenceless slot-atomic tail finalizes in-kernel.
#define BJR 512          // j-range per block
__global__ __launch_bounds__(256) void pair_kernel(
        const float* __restrict__ sq, const float* __restrict__ qual,
        int N, char* __restrict__ acc, float* __restrict__ out, unsigned nblocks) {
    __shared__ double   bsum[4];
    __shared__ unsigned bcnt[4];

    int tid = threadIdx.x;
    int i   = blockIdx.x * blockDim.x + tid;
    int j0  = blockIdx.y * BJR;

    float my_sq = (i < N) ? sq[i]   : 0.f;
    float my_q  = (i < N) ? qual[i] : -1.f;   // quality >= 0 -> all pairs masked off
    float a     = MARGIN - my_sq;

    float    sum = 0.f;
    unsigned c   = 0;
    int jmax = N - j0; if (jmax > BJR) jmax = BJR;

    if ((jmax & 3) == 0) {
        const float4* sq4 = (const float4*)(sq   + j0);
        const float4* qu4 = (const float4*)(qual + j0);
        #pragma unroll 8
        for (int j = 0; j < jmax / 4; ++j) {
            float4 sv = sq4[j];
            float4 qv = qu4[j];
            bool m0 = my_q > qv.x;  float v0 = fmaxf(a + sv.x, 0.f);
            bool m1 = my_q > qv.y;  float v1 = fmaxf(a + sv.y, 0.f);
            bool m2 = my_q > qv.z;  float v2 = fmaxf(a + sv.z, 0.f);
            bool m3 = my_q > qv.w;  float v3 = fmaxf(a + sv.w, 0.f);
            sum += m0 ? v0 : 0.f;   c += m0;
            sum += m1 ? v1 : 0.f;   c += m1;
            sum += m2 ? v2 : 0.f;   c += m2;
            sum += m3 ? v3 : 0.f;   c += m3;
        }
    } else {
        for (int j = 0; j < jmax; ++j) {
            bool  m = my_q > qual[j0 + j];
            float v = fmaxf(a + sq[j0 + j], 0.f);
            sum += m ? v : 0.f;
            c   += m ? 1u : 0u;
        }
    }

    #pragma unroll
    for (int off = 32; off >= 1; off >>= 1) {
        sum += __shfl_xor(sum, off);
        c   += __shfl_xor(c,   off);
    }
    int w = tid >> 6;
    if ((tid & 63) == 0) { bsum[w] = (double)sum; bcnt[w] = c; }
    __syncthreads();

    if (tid >= 64) return;

    unsigned last = 0;
    if (tid == 0) {
        double   bs = bsum[0] + bsum[1] + bsum[2] + bsum[3];
        unsigned bc = bcnt[0] + bcnt[1] + bcnt[2] + bcnt[3];
        unsigned bid = blockIdx.y * gridDim.x + blockIdx.x;
        unsigned s   = bid & (NSLOT - 1);

        // slot accumulate (distinct 64B lines; <=16 RMWs per line)
        double   old  = atomicAdd((double*)  (acc + (size_t)s * 64), bs);
        unsigned oldc = atomicAdd((unsigned*)(acc + 2048 + (size_t)s * 64), bc);
        // consume returns -> both RMWs are PERFORMED at the device-coherent
        // point before the arrival increment issues (fence-free ordering).
        asm volatile("" :: "v"(__double2hiint(old)), "v"(__double2loint(old)), "v"(oldc));

        unsigned gsz = (nblocks > s) ? ((nblocks - 1u - s) / NSLOT + 1u) : 0u;
        unsigned pa  = atomicAdd((unsigned*)(acc + 4096 + (size_t)s * 64), 1u);
        if (pa == gsz - 1u) {                       // slot winner
            asm volatile("" :: "v"(pa));
            unsigned nslots = (nblocks < NSLOT) ? nblocks : NSLOT;
            unsigned pm = atomicAdd((unsigned*)(acc + 6144), 1u);
            last = (pm == nslots - 1u) ? 1u : 0u;   // overall last block
        }
    }
    last = __shfl(last, 0);
    if (last) {
        double s = 0.0; ull c2 = 0ull;
        if (tid < NSLOT) {
            s  = atomicAdd((double*)  (acc + (size_t)tid * 64), 0.0);
            c2 = (ull)atomicAdd((unsigned*)(acc + 2048 + (size_t)tid * 64), 0u);
        }
        #pragma unroll
        for (int off = 16; off >= 1; off >>= 1) {
            s  += __shfl_xor(s,  off);
            c2 += __shfl_xor(c2, off);
        }
        if (tid == 0) {
            if (c2 < 1ull) c2 = 1ull;
            out[0] = (float)(s / (double)c2);
        }
    }
}

extern "C" void kernel_launch(void* const* d_in, const int* in_sizes, int n_in,
                              void* d_out, int out_size, void* d_ws, size_t ws_size,
                              hipStream_t stream) {
    const float* q_emb  = (const float*)d_in[0];
    const float* d_embs = (const float*)d_in[1];
    // d_in[2] = c_emb: computed-but-unused in the reference; skipped.
    const float* rates  = (const float*)d_in[3];

    int D = in_sizes[0];
    int N = in_sizes[3];

    char*  acc  = (char*)d_ws;
    float* sq   = (float*)(acc + 8192);
    float* qual = sq + N;
    float* out  = (float*)d_out;

    // 4 waves/block, 4 rows/wave -> N/16 blocks = 512 at N=8192
    int nblk1 = (N + 15) / 16;
    sq_kernel<<<nblk1, 256, 0, stream>>>(q_emb, d_embs, rates, sq, qual, acc, N, D);

    dim3 grid((N + 255) / 256, (N + BJR - 1) / BJR);   // 32 x 16 = 512 blocks
    pair_kernel<<<grid, 256, 0, stream>>>(sq, qual, N, acc, out,
                                          grid.x * grid.y);
}

// Round 8
// 22.605 us; speedup vs baseline: 1.2251x; 1.2251x over previous
//
#include <hip/hip_runtime.h>

#define MARGIN 0.3f
#define ANCHOR 0.5f
#define EPS    1e-8f
#define BJ     256
#define NSLOT  32        // accumulator slots, each on its own 64B line

typedef unsigned long long ull;

// ws accumulator layout (all 64B-padded):
//   gsum[k] : ws + k*64            (double)
//   gcnt[k] : ws + 2048 + k*64     (unsigned)
//   arr[k]  : ws + 4096 + k*64     (unsigned)
//   master  : ws + 6144            (unsigned)
//   sq[N]   : ws + 8192            (float)
//   qual[N] : sq + N               (float)

// ---------------- kernel 1: s_q, quality, accumulator zero-init ----------------
// One wave per row (2048 blocks at N=8192) — best-measured config (R5).
__global__ __launch_bounds__(256) void sq_kernel(
        const float* __restrict__ q, const float* __restrict__ d,
        const float* __restrict__ rates,
        float* __restrict__ sq, float* __restrict__ qual,
        char* __restrict__ acc, int N, int D) {
    int tid = threadIdx.x;
    if (blockIdx.x == 0) {
        if (tid < NSLOT)              *(double*)  (acc + (size_t)tid * 64)               = 0.0;
        else if (tid < 2 * NSLOT)     *(unsigned*)(acc + 2048 + (size_t)(tid - 32) * 64) = 0u;
        else if (tid < 3 * NSLOT)     *(unsigned*)(acc + 4096 + (size_t)(tid - 64) * 64) = 0u;
        else if (tid == 3 * NSLOT)    *(unsigned*)(acc + 6144)                           = 0u;
    }
    int wave = (blockIdx.x * blockDim.x + tid) >> 6;
    int lane = tid & 63;
    if (wave >= N) return;
    const float* row = d + (size_t)wave * (size_t)D;

    float dot = 0.f, dn = 0.f, qn = 0.f;
    for (int it = lane * 4; it < D; it += 256) {
        float4 dv = *(const float4*)(row + it);
        float4 qv = *(const float4*)(q + it);
        dot += dv.x * qv.x + dv.y * qv.y + dv.z * qv.z + dv.w * qv.w;
        dn  += dv.x * dv.x + dv.y * dv.y + dv.z * dv.z + dv.w * dv.w;
        qn  += qv.x * qv.x + qv.y * qv.y + qv.z * qv.z + qv.w * qv.w;
    }
    #pragma unroll
    for (int off = 32; off >= 1; off >>= 1) {
        dot += __shfl_xor(dot, off);
        dn  += __shfl_xor(dn,  off);
        qn  += __shfl_xor(qn,  off);
    }
    if (lane == 0) {
        float den = fmaxf(sqrtf(dn) * sqrtf(qn), EPS);
        sq[wave]   = dot / den;
        qual[wave] = fabsf(rates[wave] - ANCHOR);
    }
}

// -------- kernel 2: N^2 pair partials; count on SCALAR pipe via ballot ---------
// grid = (N/256, N/BJ). LDS float2 j-tile (uniform ds_read_b64 broadcast);
// per j: v_cmp -> vcc, add/max/cndmask/add on VALU (sum, exact fmax kept),
// count = popcount(ballot) accumulated on the scalar ALU in parallel.
__global__ __launch_bounds__(256) void pair_kernel(
        const float* __restrict__ sq, const float* __restrict__ qual,
        int N, char* __restrict__ acc, float* __restrict__ out, unsigned nblocks) {
    __shared__ float2   tile[BJ];
    __shared__ double   bsum[4];
    __shared__ unsigned bcnt[4];

    int tid = threadIdx.x;
    int i   = blockIdx.x * blockDim.x + tid;
    int j0  = blockIdx.y * BJ;

    if (tid < BJ) {
        int j = j0 + tid;
        tile[tid] = make_float2(j < N ? sq[j]   : 0.f,
                                j < N ? qual[j] : 1e30f);   // never counted
    }
    __syncthreads();

    float my_sq = (i < N) ? sq[i]   : 0.f;
    float my_q  = (i < N) ? qual[i] : -1.f;   // quality >= 0 -> all pairs masked off
    float a     = MARGIN - my_sq;

    float    sum = 0.f;
    unsigned c   = 0;                          // wave-uniform (scalar) count
    #pragma unroll 8
    for (int j = 0; j < BJ; ++j) {
        float2 t = tile[j];
        bool  m = my_q > t.y;
        float v = fmaxf(a + t.x, 0.f);
        sum += m ? v : 0.f;
        c   += (unsigned)__popcll(__ballot(m));   // s_bcnt1 + s_add on scalar pipe
    }

    #pragma unroll
    for (int off = 32; off >= 1; off >>= 1)
        sum += __shfl_xor(sum, off);

    int w = tid >> 6;
    if ((tid & 63) == 0) { bsum[w] = (double)sum; bcnt[w] = c; }
    __syncthreads();

    if (tid >= 64) return;

    unsigned last = 0;
    if (tid == 0) {
        double   bs = bsum[0] + bsum[1] + bsum[2] + bsum[3];
        unsigned bc = bcnt[0] + bcnt[1] + bcnt[2] + bcnt[3];
        unsigned bid = blockIdx.y * gridDim.x + blockIdx.x;
        unsigned s   = bid & (NSLOT - 1);

        // slot accumulate (distinct 64B lines; <=32 RMWs per line)
        double   old  = atomicAdd((double*)  (acc + (size_t)s * 64), bs);
        unsigned oldc = atomicAdd((unsigned*)(acc + 2048 + (size_t)s * 64), bc);
        // consume returns -> both RMWs are PERFORMED at the device-coherent
        // point before the arrival increment issues (fence-free ordering).
        asm volatile("" :: "v"(__double2hiint(old)), "v"(__double2loint(old)), "v"(oldc));

        unsigned gsz = (nblocks > s) ? ((nblocks - 1u - s) / NSLOT + 1u) : 0u;
        unsigned pa  = atomicAdd((unsigned*)(acc + 4096 + (size_t)s * 64), 1u);
        if (pa == gsz - 1u) {                       // slot winner
            asm volatile("" :: "v"(pa));
            unsigned nslots = (nblocks < NSLOT) ? nblocks : NSLOT;
            unsigned pm = atomicAdd((unsigned*)(acc + 6144), 1u);
            last = (pm == nslots - 1u) ? 1u : 0u;   // overall last block
        }
    }
    last = __shfl(last, 0);
    if (last) {
        double s = 0.0; ull c2 = 0ull;
        if (tid < NSLOT) {
            s  = atomicAdd((double*)  (acc + (size_t)tid * 64), 0.0);
            c2 = (ull)atomicAdd((unsigned*)(acc + 2048 + (size_t)tid * 64), 0u);
        }
        #pragma unroll
        for (int off = 16; off >= 1; off >>= 1) {
            s  += __shfl_xor(s,  off);
            c2 += __shfl_xor(c2, off);
        }
        if (tid == 0) {
            if (c2 < 1ull) c2 = 1ull;
            out[0] = (float)(s / (double)c2);
        }
    }
}

extern "C" void kernel_launch(void* const* d_in, const int* in_sizes, int n_in,
                              void* d_out, int out_size, void* d_ws, size_t ws_size,
                              hipStream_t stream) {
    const float* q_emb  = (const float*)d_in[0];
    const float* d_embs = (const float*)d_in[1];
    // d_in[2] = c_emb: computed-but-unused in the reference; skipped.
    const float* rates  = (const float*)d_in[3];

    int D = in_sizes[0];
    int N = in_sizes[3];

    char*  acc  = (char*)d_ws;
    float* sq   = (float*)(acc + 8192);
    float* qual = sq + N;
    float* out  = (float*)d_out;

    int rows_per_block = 256 / 64;   // 4 waves/block, 1 row/wave
    sq_kernel<<<(N + rows_per_block - 1) / rows_per_block, 256, 0, stream>>>(
        q_emb, d_embs, rates, sq, qual, acc, N, D);

    dim3 grid((N + 255) / 256, (N + BJ - 1) / BJ);
    pair_kernel<<<grid, 256, 0, stream>>>(sq, qual, N, acc, out,
                                          grid.x * grid.y);
}